// Round 14
// baseline (758.398 us; speedup 1.0000x reference)
//
#include <hip/hip_runtime.h>
#include <cmath>
#include <cstdint>
#include <cstddef>

// 4-layer post-LN transformer encoder, bf16 MFMA compute, bf16 residual.
// B=2 S=2048 D=768 H=12 HD=64 F=3072.

typedef __bf16 bf16_t;
typedef __bf16 bf16x8 __attribute__((ext_vector_type(8)));
typedef __bf16 bf16x4 __attribute__((ext_vector_type(4)));
typedef float  f32x4  __attribute__((ext_vector_type(4)));
typedef float  f32x16 __attribute__((ext_vector_type(16)));
typedef int    i32x2  __attribute__((ext_vector_type(2)));

#define DEV static __device__ __forceinline__

constexpr int Lc = 4, Bc = 2, Sc = 2048, Dc = 768, Hc = 12, Fc = 3072, HDc = 64;
constexpr int Mrows = Bc * Sc;  // 4096
constexpr size_t nActC = (size_t)Mrows * Dc;
// softmax scale folded into Q: (1/sqrt(64)) * log2(e)
#define QSCALE 0.18033688011112042f

DEV f32x4 mfma16(bf16x8 a, bf16x8 b, f32x4 c) {
  return __builtin_amdgcn_mfma_f32_16x16x32_bf16(a, b, c, 0, 0, 0);
}
DEV f32x16 mfma32(bf16x8 a, bf16x8 b, f32x16 c) {
  return __builtin_amdgcn_mfma_f32_32x32x16_bf16(a, b, c, 0, 0, 0);
}

DEV void gload_lds16(const void* g, void* l) {
  __builtin_amdgcn_global_load_lds(
      (const __attribute__((address_space(1))) void*)g,
      (__attribute__((address_space(3))) void*)l,
      16, 0, 0);
}

DEV float fexp2(float x) { return __builtin_amdgcn_exp2f(x); }

DEV unsigned cvtpk(float lo, float hi_) {
  unsigned r;
  asm("v_cvt_pk_bf16_f32 %0, %1, %2" : "=v"(r) : "v"(lo), "v"(hi_));
  return r;
}
DEV void swapl(unsigned &a, unsigned &b) {
  i32x2 r = __builtin_amdgcn_permlane32_swap((int)a, (int)b, false, false);
  a = (unsigned)r[0];
  b = (unsigned)r[1];
}
DEV bf16x8 frag4(unsigned a, unsigned b, unsigned c, unsigned d) {
  union { unsigned u[4]; bf16x8 v; } x;
  x.u[0] = a; x.u[1] = b; x.u[2] = c; x.u[3] = d;
  return x.v;
}

#define WAITV(N) asm volatile("s_waitcnt vmcnt(" #N ")" ::: "memory")
#define BARRIER() do { __builtin_amdgcn_s_barrier(); asm volatile("" ::: "memory"); } while (0)

// ---------------- elementwise helpers ----------------

__global__ __launch_bounds__(256) void cvt_weights_kernel(
    const float* __restrict__ Wq, const float* __restrict__ Wk,
    const float* __restrict__ Wv, const float* __restrict__ Wo,
    const float* __restrict__ W1, const float* __restrict__ W2,
    bf16_t* __restrict__ wqkv, bf16_t* __restrict__ wo,
    bf16_t* __restrict__ w1, bf16_t* __restrict__ w2) {
  constexpr int DD = Dc * Dc;
  constexpr int nDD = Lc * DD;
  constexpr int nFD = Lc * Fc * Dc;
  int i = (blockIdx.x * 256 + threadIdx.x) * 4;
  const float* src;
  bf16_t* dst;
  if (i < 3 * nDD) {
    int sub = i / nDD, r = i - sub * nDD;
    int l = r / DD, off = r - l * DD;
    src = (sub == 0 ? Wq : (sub == 1 ? Wk : Wv)) + r;
    dst = wqkv + (size_t)(l * 3 + sub) * DD + off;
  } else if (i < 4 * nDD) {
    int r = i - 3 * nDD;
    src = Wo + r; dst = wo + r;
  } else if (i < 4 * nDD + nFD) {
    int r = i - 4 * nDD;
    src = W1 + r; dst = w1 + r;
  } else {
    int r = i - 4 * nDD - nFD;
    src = W2 + r; dst = w2 + r;
  }
  float4 v = *(const float4*)src;
  bf16x4 o;
  o[0] = (bf16_t)v.x; o[1] = (bf16_t)v.y; o[2] = (bf16_t)v.z; o[3] = (bf16_t)v.w;
  *(bf16x4*)dst = o;
}

__global__ __launch_bounds__(256) void init_x_kernel(const float* __restrict__ in,
                                                     bf16_t* __restrict__ xb, int n) {
  int i = (blockIdx.x * 256 + threadIdx.x) * 4;
  if (i + 3 < n) {
    float4 v = *(const float4*)(in + i);
    bf16x4 o;
    o[0] = (bf16_t)v.x; o[1] = (bf16_t)v.y; o[2] = (bf16_t)v.z; o[3] = (bf16_t)v.w;
    *(bf16x4*)(xb + i) = o;
  }
}

// mask (B,S,S) int -> maskT[b][kw][q] u64, bit i of word = mask[b][q][kw*64+i]
__global__ __launch_bounds__(256) void mask_packT_kernel(const int* __restrict__ m,
                                                         unsigned long long* __restrict__ bits) {
  size_t gid = (size_t)blockIdx.x * 256 + threadIdx.x;
  int l = (int)(gid & 63);
  size_t widx = gid >> 6;                 // (b*(S/64)+kw)*S + q
  size_t q = widx & (Sc - 1);
  size_t bkw = widx >> 11;                // b*(S/64) + kw
  size_t kw = bkw & (Sc / 64 - 1);
  size_t b = bkw >> 5;
  unsigned long long bm = __ballot(m[(b * Sc + q) * Sc + kw * 64 + l] != 0);
  if (l == 0) bits[widx] = bm;
}

// ---------------- FFN1 GEMM: relu(A*B^T + bias) -> bf16 ------------------
// BM=64 BN=128, dbuf LDS, counted vmcnt(6): stage(kt+1) -> vmcnt(6) ->
// barrier -> compute(kt) -> barrier. Prefetch stays in flight (T4).
__global__ __launch_bounds__(256) void gemm_ffn1(const bf16_t* __restrict__ A,
                                                 const bf16_t* __restrict__ Bm,
                                                 const float* __restrict__ bias,
                                                 bf16_t* __restrict__ Cb,
                                                 int M, int N, int K) {
  __shared__ bf16_t sA[2 * 64 * 64];
  __shared__ bf16_t sB[2 * 128 * 64];
  const int tid = threadIdx.x;
  const int w = tid >> 6, l = tid & 63, lg = l >> 4, li = l & 15;
  const int wr = w >> 1, wc = w & 1;
  const int nwg = gridDim.x, cpx = nwg >> 3;
  const int id = blockIdx.x;
  const int tid2 = (id & 7) * cpx + (id >> 3);
  const int nbx = M / 64;
  const int tm = (tid2 % nbx) * 64, tn = (tid2 / nbx) * 128;
  const int nk = K >> 6;

  f32x4 acc[2][4];
#pragma unroll
  for (int m = 0; m < 2; m++)
#pragma unroll
    for (int n = 0; n < 4; n++) acc[m][n] = (f32x4){0.f, 0.f, 0.f, 0.f};

  auto stage = [&](int buf, int kt) {
    const int k0 = kt * 64;
#pragma unroll
    for (int i = 0; i < 2; i++) {
      int off = i * 2048 + tid * 8;
      gload_lds16(A + (size_t)(tm + (off >> 6)) * K + k0 + (off & 63),
                  &sA[buf * 4096 + i * 2048 + w * 512]);
    }
#pragma unroll
    for (int i = 0; i < 4; i++) {
      int off = i * 2048 + tid * 8;
      gload_lds16(Bm + (size_t)(tn + (off >> 6)) * K + k0 + (off & 63),
                  &sB[buf * 8192 + i * 2048 + w * 512]);
    }
  };

  stage(0, 0);
  WAITV(0);
  BARRIER();
  int cur = 0;
  for (int kt = 0; kt < nk; kt++) {
    if (kt + 1 < nk) {
      stage(cur ^ 1, kt + 1);
      WAITV(6);
    } else {
      WAITV(0);
    }
    BARRIER();
    const bf16_t* sAb = &sA[cur * 4096];
    const bf16_t* sBb = &sB[cur * 8192];
#pragma unroll
    for (int kk = 0; kk < 2; kk++) {
      bf16x8 af[2], bfr[4];
#pragma unroll
      for (int m = 0; m < 2; m++)
        af[m] = *(const bf16x8*)&sAb[(wr * 32 + m * 16 + li) * 64 + kk * 32 + lg * 8];
#pragma unroll
      for (int n = 0; n < 4; n++)
        bfr[n] = *(const bf16x8*)&sBb[(wc * 64 + n * 16 + li) * 64 + kk * 32 + lg * 8];
#pragma unroll
      for (int m = 0; m < 2; m++)
#pragma unroll
        for (int n = 0; n < 4; n++)
          acc[m][n] = mfma16(af[m], bfr[n], acc[m][n]);
    }
    BARRIER();
    cur ^= 1;
  }

#pragma unroll
  for (int m = 0; m < 2; m++) {
    int rbase = tm + wr * 32 + m * 16 + lg * 4;
#pragma unroll
    for (int n = 0; n < 4; n++) {
      int c = tn + wc * 64 + n * 16 + li;
      float bv = bias[c];
#pragma unroll
      for (int j = 0; j < 4; j++)
        Cb[(size_t)(rbase + j) * N + c] = (bf16_t)fmaxf(acc[m][n][j] + bv, 0.f);
    }
  }
}

// ---------------- split-K GEMM (Wo / FFN2): partial = A*B^T -> bf16 ------
// SPLIT-way split-K; partial s lands at Pbase + s*nActC.
template <int SPLIT>
__global__ __launch_bounds__(256) void gemm_sk(const bf16_t* __restrict__ A,
                                               const bf16_t* __restrict__ Bm,
                                               bf16_t* __restrict__ Pbase,
                                               int M, int N, int K) {
  __shared__ bf16_t sA[2 * 64 * 64];
  __shared__ bf16_t sB[2 * 128 * 64];
  const int tid = threadIdx.x;
  const int w = tid >> 6, l = tid & 63, lg = l >> 4, li = l & 15;
  const int wr = w >> 1, wc = w & 1;
  const int nwg = gridDim.x, cpx = nwg >> 3;
  const int id = blockIdx.x;
  const int tid2 = (id & 7) * cpx + (id >> 3);
  const int nper = nwg / SPLIT;
  const int ks = tid2 / nper;
  const int r = tid2 - ks * nper;
  const int nbx = M / 64;
  const int tm = (r % nbx) * 64, tn = (r / nbx) * 128;
  const int kB = K / SPLIT;
  const int k0base = ks * kB;
  const int nk = kB >> 6;
  bf16_t* __restrict__ P = Pbase + (size_t)ks * nActC;

  f32x4 acc[2][4];
#pragma unroll
  for (int m = 0; m < 2; m++)
#pragma unroll
    for (int n = 0; n < 4; n++) acc[m][n] = (f32x4){0.f, 0.f, 0.f, 0.f};

  auto stage = [&](int buf, int kt) {
    const int k0 = k0base + kt * 64;
#pragma unroll
    for (int i = 0; i < 2; i++) {
      int off = i * 2048 + tid * 8;
      gload_lds16(A + (size_t)(tm + (off >> 6)) * K + k0 + (off & 63),
                  &sA[buf * 4096 + i * 2048 + w * 512]);
    }
#pragma unroll
    for (int i = 0; i < 4; i++) {
      int off = i * 2048 + tid * 8;
      gload_lds16(Bm + (size_t)(tn + (off >> 6)) * K + k0 + (off & 63),
                  &sB[buf * 8192 + i * 2048 + w * 512]);
    }
  };

  stage(0, 0);
  WAITV(0);
  BARRIER();
  int cur = 0;
  for (int kt = 0; kt < nk; kt++) {
    if (kt + 1 < nk) {
      stage(cur ^ 1, kt + 1);
      WAITV(6);
    } else {
      WAITV(0);
    }
    BARRIER();
    const bf16_t* sAb = &sA[cur * 4096];
    const bf16_t* sBb = &sB[cur * 8192];
#pragma unroll
    for (int kk = 0; kk < 2; kk++) {
      bf16x8 af[2], bfr[4];
#pragma unroll
      for (int m = 0; m < 2; m++)
        af[m] = *(const bf16x8*)&sAb[(wr * 32 + m * 16 + li) * 64 + kk * 32 + lg * 8];
#pragma unroll
      for (int n = 0; n < 4; n++)
        bfr[n] = *(const bf16x8*)&sBb[(wc * 64 + n * 16 + li) * 64 + kk * 32 + lg * 8];
#pragma unroll
      for (int m = 0; m < 2; m++)
#pragma unroll
        for (int n = 0; n < 4; n++)
          acc[m][n] = mfma16(af[m], bfr[n], acc[m][n]);
    }
    BARRIER();
    cur ^= 1;
  }

#pragma unroll
  for (int m = 0; m < 2; m++) {
    int rbase = tm + wr * 32 + m * 16 + lg * 4;
#pragma unroll
    for (int n = 0; n < 4; n++) {
      int c = tn + wc * 64 + n * 16 + li;
#pragma unroll
      for (int j = 0; j < 4; j++)
        P[(size_t)(rbase + j) * N + c] = (bf16_t)acc[m][n][j];
    }
  }
}

// ---------------- fused QKV GEMM: 64x128 tile, dbuf, counted vmcnt -------
__global__ __launch_bounds__(256) void gemm_qkv(const bf16_t* __restrict__ A,
                                                const bf16_t* __restrict__ Bm,
                                                const float* __restrict__ bq,
                                                const float* __restrict__ bk,
                                                const float* __restrict__ bv,
                                                bf16_t* __restrict__ qo,
                                                bf16_t* __restrict__ ko,
                                                bf16_t* __restrict__ vTo) {
  constexpr int K = Dc;
  __shared__ bf16_t sA[2 * 64 * 64];
  __shared__ bf16_t sB[2 * 128 * 64];
  const int tid = threadIdx.x;
  const int w = tid >> 6, l = tid & 63, lg = l >> 4, li = l & 15;
  const int wr = w >> 1, wc = w & 1;
  const int nwg = gridDim.x, cpx = nwg >> 3;  // 1152 -> 144
  const int id = blockIdx.x;
  const int tid2 = (id & 7) * cpx + (id >> 3);
  constexpr int nbx = Mrows / 64;  // 64
  const int tm = (tid2 % nbx) * 64, tn = (tid2 / nbx) * 128;
  constexpr int nk = K >> 6;       // 12

  f32x4 acc[2][4];
#pragma unroll
  for (int m = 0; m < 2; m++)
#pragma unroll
    for (int n = 0; n < 4; n++) acc[m][n] = (f32x4){0.f, 0.f, 0.f, 0.f};

  auto stage = [&](int buf, int kt) {
    const int k0 = kt * 64;
#pragma unroll
    for (int i = 0; i < 2; i++) {
      int off = i * 2048 + tid * 8;
      gload_lds16(A + (size_t)(tm + (off >> 6)) * K + k0 + (off & 63),
                  &sA[buf * 4096 + i * 2048 + w * 512]);
    }
#pragma unroll
    for (int i = 0; i < 4; i++) {
      int off = i * 2048 + tid * 8;
      gload_lds16(Bm + (size_t)(tn + (off >> 6)) * K + k0 + (off & 63),
                  &sB[buf * 8192 + i * 2048 + w * 512]);
    }
  };

  stage(0, 0);
  WAITV(0);
  BARRIER();
  int cur = 0;
  for (int kt = 0; kt < nk; kt++) {
    if (kt + 1 < nk) {
      stage(cur ^ 1, kt + 1);
      WAITV(6);
    } else {
      WAITV(0);
    }
    BARRIER();
    const bf16_t* sAb = &sA[cur * 4096];
    const bf16_t* sBb = &sB[cur * 8192];
#pragma unroll
    for (int kk = 0; kk < 2; kk++) {
      bf16x8 af[2], bfr[4];
#pragma unroll
      for (int m = 0; m < 2; m++)
        af[m] = *(const bf16x8*)&sAb[(wr * 32 + m * 16 + li) * 64 + kk * 32 + lg * 8];
#pragma unroll
      for (int n = 0; n < 4; n++)
        bfr[n] = *(const bf16x8*)&sBb[(wc * 64 + n * 16 + li) * 64 + kk * 32 + lg * 8];
#pragma unroll
      for (int m = 0; m < 2; m++)
#pragma unroll
        for (int n = 0; n < 4; n++)
          acc[m][n] = mfma16(af[m], bfr[n], acc[m][n]);
    }
    BARRIER();
    cur ^= 1;
  }

  const int which = tn / 768;  // 768 % 128 == 0 -> uniform per block
#pragma unroll
  for (int m = 0; m < 2; m++) {
    int rbase = tm + wr * 32 + m * 16 + lg * 4;
#pragma unroll
    for (int n = 0; n < 4; n++) {
      int c = tn + wc * 64 + n * 16 + li;
      int col = c - which * 768;
      if (which == 0) {
        float bvv = bq[col];
#pragma unroll
        for (int j = 0; j < 4; j++)
          qo[(size_t)(rbase + j) * Dc + col] = (bf16_t)((acc[m][n][j] + bvv) * QSCALE);
      } else if (which == 1) {
        float bvv = bk[col];
#pragma unroll
        for (int j = 0; j < 4; j++)
          ko[(size_t)(rbase + j) * Dc + col] = (bf16_t)(acc[m][n][j] + bvv);
      } else {
        float bvv = bv[col];
        int h = col >> 6, d = col & 63;
        int b = rbase >> 11, s0 = rbase & 2047;
        bf16x4 pk;
#pragma unroll
        for (int j = 0; j < 4; j++) pk[j] = (bf16_t)(acc[m][n][j] + bvv);
        *(bf16x4*)(vTo + ((size_t)(b * Hc + h) * HDc + d) * Sc + s0) = pk;
      }
    }
  }
}

// ---------------- flash attention v7 (proven version, unchanged) --------
__global__ __launch_bounds__(256) void attn7_kernel(
    const bf16_t* __restrict__ q, const bf16_t* __restrict__ k,
    const bf16_t* __restrict__ vT, const unsigned long long* __restrict__ maskT,
    bf16_t* __restrict__ ctx) {
  __shared__ __align__(16) char smem[32768];

  const int t = threadIdx.x, w = t >> 6, l = t & 63;
  const int hi = l >> 5, li = l & 31;
  const int wp = w & 1, kvh = w >> 1;
  const int gid = blockIdx.x;
  const int tid2 = (gid & 7) * 96 + (gid >> 3);
  const int bh = tid2 >> 5, qt = tid2 & 31;
  const int b = bh / Hc, h = bh - b * Hc;
  const int qrow = qt * 64 + wp * 32 + li;

  const bf16_t* qp = q + (size_t)(b * Sc + qrow) * Dc + h * HDc + hi * 8;
  bf16x8 qf[4];
#pragma unroll
  for (int dk = 0; dk < 4; dk++) qf[dk] = *(const bf16x8*)(qp + dk * 16);

  const bf16_t* kg = k + ((size_t)(b * Sc) + kvh * 1024) * Dc + h * HDc;
  const bf16_t* vg = vT + (size_t)bh * HDc * Sc + kvh * 1024;
  const unsigned long long* mg =
      maskT + (size_t)b * 32 * Sc + (size_t)(kvh * 16) * Sc + qrow;

  f32x16 o0, o1;
#pragma unroll
  for (int r = 0; r < 16; r++) { o0[r] = 0.f; o1[r] = 0.f; }
  float ps = 0.f;

  auto stage = [&](int buf, int c) {
    const int kv0 = c * 32;
    bf16_t* sk = (bf16_t*)(smem + kvh * 16384 + buf * 8192);
    bf16_t* sv = (bf16_t*)(smem + kvh * 16384 + buf * 8192 + 4096);
#pragma unroll
    for (int i = 0; i < 2; i++) {
      int s = i * 128 + wp * 64 + l;
      int row = s >> 3, ch = s & 7;
      gload_lds16(kg + (size_t)(kv0 + row) * Dc + ((ch ^ (row & 7)) * 8),
                  sk + (i * 128 + wp * 64) * 8);
    }
#pragma unroll
    for (int i = 0; i < 2; i++) {
      int s = i * 128 + wp * 64 + l;
      int row = s >> 2, ch = s & 3;
      gload_lds16(vg + (size_t)row * Sc + kv0 + ((ch ^ ((row >> 1) & 3)) * 8),
                  sv + (i * 128 + wp * 64) * 8);
    }
  };

  stage(0, 0);
  __syncthreads();
  int cur = 0;
  unsigned long long mw = 0;
#pragma unroll 2
  for (int c = 0; c < 32; c++) {
    if (c + 1 < 32) stage(cur ^ 1, c + 1);
    if ((c & 1) == 0) mw = mg[(size_t)(c >> 1) * Sc];
    unsigned msel = (c & 1) ? (unsigned)(mw >> 32) : (unsigned)mw;
    unsigned ms0 = msel >> (hi * 4);

    f32x16 sc0;
#pragma unroll
    for (int r = 0; r < 16; r++) sc0[r] = 0.f;
    const bf16_t* kb = (const bf16_t*)(smem + kvh * 16384 + cur * 8192);
    __builtin_amdgcn_s_setprio(1);
#pragma unroll
    for (int dk = 0; dk < 4; dk++) {
      int ch = dk * 2 + hi;
      bf16x8 ka0 = *(const bf16x8*)(kb + li * 64 + ((ch ^ (li & 7)) * 8));
      sc0 = mfma32(ka0, qf[dk], sc0);
    }
    __builtin_amdgcn_s_setprio(0);

    unsigned pw[8];
#pragma unroll
    for (int r = 0; r < 16; r += 2) {
      int kbit = (r & 3) + 8 * (r >> 2);
      float a0 = fexp2(sc0[r]), a1 = fexp2(sc0[r + 1]);
      a0 = ((ms0 >> kbit) & 1u) ? 0.f : a0;
      a1 = ((ms0 >> (kbit + 1)) & 1u) ? 0.f : a1;
      ps += a0 + a1;
      pw[r >> 1] = cvtpk(a0, a1);
    }
    swapl(pw[0], pw[2]);  swapl(pw[1], pw[3]);
    swapl(pw[4], pw[6]);  swapl(pw[5], pw[7]);
    bf16x8 pb0 = frag4(pw[0], pw[1], pw[2], pw[3]);
    bf16x8 pb1 = frag4(pw[4], pw[5], pw[6], pw[7]);

    const bf16_t* vb = (const bf16_t*)(smem + kvh * 16384 + cur * 8192 + 4096);
    __builtin_amdgcn_s_setprio(1);
#pragma unroll
    for (int g = 0; g < 2; g++) {
      int ch = g * 2 + hi;
      bf16x8 va0 = *(const bf16x8*)(vb + li * 32 + ((ch ^ ((li >> 1) & 3)) * 8));
      bf16x8 va1 = *(const bf16x8*)(vb + (32 + li) * 32 + ((ch ^ ((li >> 1) & 3)) * 8));
      bf16x8 pbg = (g == 0) ? pb0 : pb1;
      o0 = mfma32(va0, pbg, o0);
      o1 = mfma32(va1, pbg, o1);
    }
    __builtin_amdgcn_s_setprio(0);
    __syncthreads();
    cur ^= 1;
  }

  float* mp = (float*)(smem + 16384);
  if (kvh == 1) {
    char* base = smem + wp * 8192 + l * 128;
#pragma unroll
    for (int r = 0; r < 4; r++) {
      *(f32x4*)(base + ((r ^ (l & 7)) * 16)) =
          (f32x4){o0[r * 4], o0[r * 4 + 1], o0[r * 4 + 2], o0[r * 4 + 3]};
      *(f32x4*)(base + (((r + 4) ^ (l & 7)) * 16)) =
          (f32x4){o1[r * 4], o1[r * 4 + 1], o1[r * 4 + 2], o1[r * 4 + 3]};
    }
    mp[wp * 64 + l] = ps;
  }
  __syncthreads();
  float inv = 0.f;
  if (kvh == 0) {
    char* base = smem + wp * 8192 + l * 128;
#pragma unroll
    for (int r = 0; r < 4; r++) {
      f32x4 u = *(const f32x4*)(base + ((r ^ (l & 7)) * 16));
      f32x4 v = *(const f32x4*)(base + (((r + 4) ^ (l & 7)) * 16));
#pragma unroll
      for (int j = 0; j < 4; j++) { o0[r * 4 + j] += u[j]; o1[r * 4 + j] += v[j]; }
    }
    ps += mp[wp * 64 + l];
    float tot = ps + __shfl_xor(ps, 32, 64);
    inv = 1.f / tot;
  }
  __syncthreads();
  if (kvh == 0) {
    char* so = smem + wp * 4096;
    const int lx = li & 7;
#pragma unroll
    for (int g = 0; g < 4; g++) {
      unsigned u0 = cvtpk(o0[g * 4 + 0] * inv, o0[g * 4 + 1] * inv);
      unsigned u1 = cvtpk(o0[g * 4 + 2] * inv, o0[g * 4 + 3] * inv);
      unsigned v0 = cvtpk(o1[g * 4 + 0] * inv, o1[g * 4 + 1] * inv);
      unsigned v1 = cvtpk(o1[g * 4 + 2] * inv, o1[g * 4 + 3] * inv);
      *(uint2*)(so + li * 128 + ((g ^ lx) * 16) + hi * 8) = make_uint2(u0, u1);
      *(uint2*)(so + li * 128 + (((g + 4) ^ lx) * 16) + hi * 8) = make_uint2(v0, v1);
    }
    __builtin_amdgcn_s_waitcnt(0);
    bf16_t* cbase = ctx + (size_t)(b * Sc + qt * 64 + wp * 32) * Dc + h * HDc;
#pragma unroll
    for (int i = 0; i < 4; i++) {
      int s = i * 64 + l;
      int row = s >> 3, ch = s & 7;
      bf16x8 vv = *(const bf16x8*)(so + row * 128 + ((ch ^ (row & 7)) * 16));
      *(bf16x8*)(cbase + (size_t)row * Dc + ch * 8) = vv;
    }
  }
}

// ---- fused split-K reduce + bias + residual + LayerNorm (bf16 streams) --
// v = sum_p pk[p] + bias[d] + res;  x = LN(v)*g + b -> xb, optionally xo.
template <int NP>
__global__ __launch_bounds__(256) void ln_fuse_kernel(const bf16_t* __restrict__ pk,
                                                      const float* __restrict__ bias,
                                                      const bf16_t* res,
                                                      const float* __restrict__ g,
                                                      const float* __restrict__ bb,
                                                      float* xo, bf16_t* xb) {
  const int row = blockIdx.x;
  const int t = threadIdx.x;
  const size_t base = (size_t)row * Dc;
  float v0 = bias[t] + (float)res[base + t];
  float v1 = bias[t + 256] + (float)res[base + t + 256];
  float v2 = bias[t + 512] + (float)res[base + t + 512];
#pragma unroll
  for (int p = 0; p < NP; p++) {
    const bf16_t* pp = pk + (size_t)p * nActC + base;
    v0 += (float)pp[t];
    v1 += (float)pp[t + 256];
    v2 += (float)pp[t + 512];
  }
  float s = v0 + v1 + v2;
  float sq = v0 * v0 + v1 * v1 + v2 * v2;
#pragma unroll
  for (int ofs = 1; ofs < 64; ofs <<= 1) {
    s += __shfl_xor(s, ofs, 64);
    sq += __shfl_xor(sq, ofs, 64);
  }
  __shared__ float red[8];
  const int w = t >> 6, l = t & 63;
  if (l == 0) { red[w] = s; red[4 + w] = sq; }
  __syncthreads();
  s = red[0] + red[1] + red[2] + red[3];
  sq = red[4] + red[5] + red[6] + red[7];
  const float mean = s * (1.f / Dc);
  const float var = sq * (1.f / Dc) - mean * mean;
  const float rs = rsqrtf(var + 1e-5f);
  bf16_t* pb = xb + base;
#pragma unroll
  for (int i = 0; i < 3; i++) {
    int d = t + i * 256;
    float vv = (i == 0 ? v0 : (i == 1 ? v1 : v2));
    float ov = (vv - mean) * rs * g[d] + bb[d];
    if (xo) xo[base + d] = ov;
    pb[d] = (bf16_t)ov;
  }
}

// ---------------- launcher ----------------

extern "C" void kernel_launch(void* const* d_in, const int* in_sizes, int n_in,
                              void* d_out, int out_size, void* d_ws, size_t ws_size,
                              hipStream_t stream) {
  const float* inputs = (const float*)d_in[0];
  const int* amask = (const int*)d_in[1];
  const float* Wq = (const float*)d_in[2];
  const float* bq = (const float*)d_in[3];
  const float* Wk = (const float*)d_in[4];
  const float* bk = (const float*)d_in[5];
  const float* Wv = (const float*)d_in[6];
  const float* bv = (const float*)d_in[7];
  const float* Wo = (const float*)d_in[8];
  const float* bo = (const float*)d_in[9];
  const float* ln1_g = (const float*)d_in[10];
  const float* ln1_b = (const float*)d_in[11];
  const float* W1 = (const float*)d_in[12];
  const float* b1 = (const float*)d_in[13];
  const float* W2 = (const float*)d_in[14];
  const float* b2 = (const float*)d_in[15];
  const float* ln2_g = (const float*)d_in[16];
  const float* ln2_b = (const float*)d_in[17];
  float* xout = (float*)d_out;

  char* p = (char*)d_ws;
  auto carve = [&](size_t bytes) -> char* {
    char* r = p;
    p += (bytes + 255) & ~(size_t)255;
    return r;
  };
  const size_t nDD = (size_t)Lc * Dc * Dc;
  const size_t nFD = (size_t)Lc * Fc * Dc;
  const size_t nAct = nActC;
  const size_t nHid = (size_t)Mrows * Fc;

  bf16_t* wqkv16 = (bf16_t*)carve(nDD * 3 * 2);
  bf16_t* wo16 = (bf16_t*)carve(nDD * 2);
  bf16_t* w1_16 = (bf16_t*)carve(nFD * 2);
  bf16_t* w2_16 = (bf16_t*)carve(nFD * 2);
  bf16_t* xb = (bf16_t*)carve(nAct * 2);
  bf16_t* q16 = (bf16_t*)carve(nAct * 2);
  bf16_t* k16 = (bf16_t*)carve(nAct * 2);
  bf16_t* vTb = (bf16_t*)carve(nAct * 2);
  bf16_t* ctx = (bf16_t*)carve(nAct * 2);
  bf16_t* h16 = (bf16_t*)carve(nHid * 2);
  bf16_t* pkb = (bf16_t*)carve(nAct * 4 * 2);  // 4 split-K bf16 partials
  unsigned long long* maskb = (unsigned long long*)carve((size_t)Bc * (Sc / 64) * Sc * 8);
  (void)ws_size; (void)n_in; (void)in_sizes; (void)out_size;

  dim3 blk(256);

  mask_packT_kernel<<<(int)((size_t)Bc * Sc * Sc / 256), blk, 0, stream>>>(amask, maskb);
  cvt_weights_kernel<<<(int)((4 * nDD + 2 * nFD) / 1024), blk, 0, stream>>>(
      Wq, Wk, Wv, Wo, W1, W2, wqkv16, wo16, w1_16, w2_16);
  init_x_kernel<<<(int)(nAct / 1024), blk, 0, stream>>>(inputs, xb, (int)nAct);

  for (int i = 0; i < Lc; i++) {
    const bf16_t* wqkv_l = wqkv16 + (size_t)i * 3 * Dc * Dc;
    const bf16_t* wo_l = wo16 + (size_t)i * Dc * Dc;
    const bf16_t* w1_l = w1_16 + (size_t)i * Fc * Dc;
    const bf16_t* w2_l = w2_16 + (size_t)i * Dc * Fc;

    gemm_qkv<<<1152, blk, 0, stream>>>(
        xb, wqkv_l, bq + (size_t)i * Dc, bk + (size_t)i * Dc, bv + (size_t)i * Dc,
        q16, k16, vTb);

    attn7_kernel<<<768, blk, 0, stream>>>(q16, k16, vTb, maskb, ctx);

    // Wo projection, split-K=2 -> bf16 partials; LN1 fuses reduce+bias+res.
    gemm_sk<2><<<768, blk, 0, stream>>>(ctx, wo_l, pkb, Mrows, Dc, Dc);
    ln_fuse_kernel<2><<<Mrows, blk, 0, stream>>>(pkb, bo + (size_t)i * Dc, xb,
                                                 ln1_g + (size_t)i * Dc,
                                                 ln1_b + (size_t)i * Dc, nullptr, xb);
    gemm_ffn1<<<1536, blk, 0, stream>>>(
        xb, w1_l, b1 + (size_t)i * Fc, h16, Mrows, Fc, Dc);
    // FFN2, split-K=4 -> bf16 partials; LN2 fuses reduce+bias+res.
    gemm_sk<4><<<1536, blk, 0, stream>>>(h16, w2_l, pkb, Mrows, Dc, Fc);
    ln_fuse_kernel<4><<<Mrows, blk, 0, stream>>>(pkb, b2 + (size_t)i * Dc, xb,
                                                 ln2_g + (size_t)i * Dc,
                                                 ln2_b + (size_t)i * Dc,
                                                 (i == Lc - 1) ? xout : nullptr, xb);
  }
}

// Round 15
// 746.185 us; speedup vs baseline: 1.0164x; 1.0164x over previous
//
#include <hip/hip_runtime.h>
#include <cmath>
#include <cstdint>
#include <cstddef>

// 4-layer post-LN transformer encoder, bf16 MFMA compute, bf16 residual.
// B=2 S=2048 D=768 H=12 HD=64 F=3072.

typedef __bf16 bf16_t;
typedef __bf16 bf16x8 __attribute__((ext_vector_type(8)));
typedef __bf16 bf16x4 __attribute__((ext_vector_type(4)));
typedef float  f32x4  __attribute__((ext_vector_type(4)));
typedef float  f32x16 __attribute__((ext_vector_type(16)));
typedef int    i32x2  __attribute__((ext_vector_type(2)));

#define DEV static __device__ __forceinline__

constexpr int Lc = 4, Bc = 2, Sc = 2048, Dc = 768, Hc = 12, Fc = 3072, HDc = 64;
constexpr int Mrows = Bc * Sc;  // 4096
constexpr size_t nActC = (size_t)Mrows * Dc;
// softmax scale folded into Q: (1/sqrt(64)) * log2(e)
#define QSCALE 0.18033688011112042f

DEV f32x4 mfma16(bf16x8 a, bf16x8 b, f32x4 c) {
  return __builtin_amdgcn_mfma_f32_16x16x32_bf16(a, b, c, 0, 0, 0);
}
DEV f32x16 mfma32(bf16x8 a, bf16x8 b, f32x16 c) {
  return __builtin_amdgcn_mfma_f32_32x32x16_bf16(a, b, c, 0, 0, 0);
}

DEV void gload_lds16(const void* g, void* l) {
  __builtin_amdgcn_global_load_lds(
      (const __attribute__((address_space(1))) void*)g,
      (__attribute__((address_space(3))) void*)l,
      16, 0, 0);
}

DEV float fexp2(float x) { return __builtin_amdgcn_exp2f(x); }

DEV unsigned cvtpk(float lo, float hi_) {
  unsigned r;
  asm("v_cvt_pk_bf16_f32 %0, %1, %2" : "=v"(r) : "v"(lo), "v"(hi_));
  return r;
}
DEV void swapl(unsigned &a, unsigned &b) {
  i32x2 r = __builtin_amdgcn_permlane32_swap((int)a, (int)b, false, false);
  a = (unsigned)r[0];
  b = (unsigned)r[1];
}
DEV bf16x8 frag4(unsigned a, unsigned b, unsigned c, unsigned d) {
  union { unsigned u[4]; bf16x8 v; } x;
  x.u[0] = a; x.u[1] = b; x.u[2] = c; x.u[3] = d;
  return x.v;
}

#define WAITV(N) asm volatile("s_waitcnt vmcnt(" #N ")" ::: "memory")
#define BARRIER() do { __builtin_amdgcn_s_barrier(); asm volatile("" ::: "memory"); } while (0)

// ---------------- elementwise helpers ----------------

__global__ __launch_bounds__(256) void cvt_weights_kernel(
    const float* __restrict__ Wq, const float* __restrict__ Wk,
    const float* __restrict__ Wv, const float* __restrict__ Wo,
    const float* __restrict__ W1, const float* __restrict__ W2,
    bf16_t* __restrict__ wqkv, bf16_t* __restrict__ wo,
    bf16_t* __restrict__ w1, bf16_t* __restrict__ w2) {
  constexpr int DD = Dc * Dc;
  constexpr int nDD = Lc * DD;
  constexpr int nFD = Lc * Fc * Dc;
  int i = (blockIdx.x * 256 + threadIdx.x) * 4;
  const float* src;
  bf16_t* dst;
  if (i < 3 * nDD) {
    int sub = i / nDD, r = i - sub * nDD;
    int l = r / DD, off = r - l * DD;
    src = (sub == 0 ? Wq : (sub == 1 ? Wk : Wv)) + r;
    dst = wqkv + (size_t)(l * 3 + sub) * DD + off;
  } else if (i < 4 * nDD) {
    int r = i - 3 * nDD;
    src = Wo + r; dst = wo + r;
  } else if (i < 4 * nDD + nFD) {
    int r = i - 4 * nDD;
    src = W1 + r; dst = w1 + r;
  } else {
    int r = i - 4 * nDD - nFD;
    src = W2 + r; dst = w2 + r;
  }
  float4 v = *(const float4*)src;
  bf16x4 o;
  o[0] = (bf16_t)v.x; o[1] = (bf16_t)v.y; o[2] = (bf16_t)v.z; o[3] = (bf16_t)v.w;
  *(bf16x4*)dst = o;
}

__global__ __launch_bounds__(256) void init_x_kernel(const float* __restrict__ in,
                                                     bf16_t* __restrict__ xb, int n) {
  int i = (blockIdx.x * 256 + threadIdx.x) * 4;
  if (i + 3 < n) {
    float4 v = *(const float4*)(in + i);
    bf16x4 o;
    o[0] = (bf16_t)v.x; o[1] = (bf16_t)v.y; o[2] = (bf16_t)v.z; o[3] = (bf16_t)v.w;
    *(bf16x4*)(xb + i) = o;
  }
}

// mask (B,S,S) int -> maskT[b][kw][q] u64, bit i of word = mask[b][q][kw*64+i]
__global__ __launch_bounds__(256) void mask_packT_kernel(const int* __restrict__ m,
                                                         unsigned long long* __restrict__ bits) {
  size_t gid = (size_t)blockIdx.x * 256 + threadIdx.x;
  int l = (int)(gid & 63);
  size_t widx = gid >> 6;                 // (b*(S/64)+kw)*S + q
  size_t q = widx & (Sc - 1);
  size_t bkw = widx >> 11;                // b*(S/64) + kw
  size_t kw = bkw & (Sc / 64 - 1);
  size_t b = bkw >> 5;
  unsigned long long bm = __ballot(m[(b * Sc + q) * Sc + kw * 64 + l] != 0);
  if (l == 0) bits[widx] = bm;
}

// ---------------- FFN1 GEMM: relu(A*B^T + bias) -> bf16 ------------------
// BM=64 BN=128, dbuf LDS, counted vmcnt(6): stage(kt+1) -> vmcnt(6) ->
// barrier -> compute(kt) -> barrier. Prefetch stays in flight (T4).
__global__ __launch_bounds__(256) void gemm_ffn1(const bf16_t* __restrict__ A,
                                                 const bf16_t* __restrict__ Bm,
                                                 const float* __restrict__ bias,
                                                 bf16_t* __restrict__ Cb,
                                                 int M, int N, int K) {
  __shared__ bf16_t sA[2 * 64 * 64];
  __shared__ bf16_t sB[2 * 128 * 64];
  const int tid = threadIdx.x;
  const int w = tid >> 6, l = tid & 63, lg = l >> 4, li = l & 15;
  const int wr = w >> 1, wc = w & 1;
  const int nwg = gridDim.x, cpx = nwg >> 3;
  const int id = blockIdx.x;
  const int tid2 = (id & 7) * cpx + (id >> 3);
  const int nbx = M / 64;
  const int tm = (tid2 % nbx) * 64, tn = (tid2 / nbx) * 128;
  const int nk = K >> 6;

  f32x4 acc[2][4];
#pragma unroll
  for (int m = 0; m < 2; m++)
#pragma unroll
    for (int n = 0; n < 4; n++) acc[m][n] = (f32x4){0.f, 0.f, 0.f, 0.f};

  auto stage = [&](int buf, int kt) {
    const int k0 = kt * 64;
#pragma unroll
    for (int i = 0; i < 2; i++) {
      int off = i * 2048 + tid * 8;
      gload_lds16(A + (size_t)(tm + (off >> 6)) * K + k0 + (off & 63),
                  &sA[buf * 4096 + i * 2048 + w * 512]);
    }
#pragma unroll
    for (int i = 0; i < 4; i++) {
      int off = i * 2048 + tid * 8;
      gload_lds16(Bm + (size_t)(tn + (off >> 6)) * K + k0 + (off & 63),
                  &sB[buf * 8192 + i * 2048 + w * 512]);
    }
  };

  stage(0, 0);
  WAITV(0);
  BARRIER();
  int cur = 0;
  for (int kt = 0; kt < nk; kt++) {
    if (kt + 1 < nk) {
      stage(cur ^ 1, kt + 1);
      WAITV(6);
    } else {
      WAITV(0);
    }
    BARRIER();
    const bf16_t* sAb = &sA[cur * 4096];
    const bf16_t* sBb = &sB[cur * 8192];
#pragma unroll
    for (int kk = 0; kk < 2; kk++) {
      bf16x8 af[2], bfr[4];
#pragma unroll
      for (int m = 0; m < 2; m++)
        af[m] = *(const bf16x8*)&sAb[(wr * 32 + m * 16 + li) * 64 + kk * 32 + lg * 8];
#pragma unroll
      for (int n = 0; n < 4; n++)
        bfr[n] = *(const bf16x8*)&sBb[(wc * 64 + n * 16 + li) * 64 + kk * 32 + lg * 8];
#pragma unroll
      for (int m = 0; m < 2; m++)
#pragma unroll
        for (int n = 0; n < 4; n++)
          acc[m][n] = mfma16(af[m], bfr[n], acc[m][n]);
    }
    BARRIER();
    cur ^= 1;
  }

#pragma unroll
  for (int m = 0; m < 2; m++) {
    int rbase = tm + wr * 32 + m * 16 + lg * 4;
#pragma unroll
    for (int n = 0; n < 4; n++) {
      int c = tn + wc * 64 + n * 16 + li;
      float bv = bias[c];
#pragma unroll
      for (int j = 0; j < 4; j++)
        Cb[(size_t)(rbase + j) * N + c] = (bf16_t)fmaxf(acc[m][n][j] + bv, 0.f);
    }
  }
}

// ---------------- split-K GEMM (Wo / FFN2): partial = A*B^T -> bf16 ------
__global__ __launch_bounds__(256) void gemm_sk(const bf16_t* __restrict__ A,
                                               const bf16_t* __restrict__ Bm,
                                               bf16_t* __restrict__ P0,
                                               bf16_t* __restrict__ P1,
                                               int M, int N, int K) {
  __shared__ bf16_t sA[2 * 64 * 64];
  __shared__ bf16_t sB[2 * 128 * 64];
  const int tid = threadIdx.x;
  const int w = tid >> 6, l = tid & 63, lg = l >> 4, li = l & 15;
  const int wr = w >> 1, wc = w & 1;
  const int nwg = gridDim.x, cpx = nwg >> 3;
  const int id = blockIdx.x;
  const int tid2 = (id & 7) * cpx + (id >> 3);
  const int half = nwg >> 1;
  const int ks = tid2 >= half ? 1 : 0;
  const int r = tid2 - ks * half;
  const int nbx = M / 64;
  const int tm = (r % nbx) * 64, tn = (r / nbx) * 128;
  const int kB = K >> 1;
  const int k0base = ks * kB;
  const int nk = kB >> 6;
  bf16_t* __restrict__ P = ks ? P1 : P0;

  f32x4 acc[2][4];
#pragma unroll
  for (int m = 0; m < 2; m++)
#pragma unroll
    for (int n = 0; n < 4; n++) acc[m][n] = (f32x4){0.f, 0.f, 0.f, 0.f};

  auto stage = [&](int buf, int kt) {
    const int k0 = k0base + kt * 64;
#pragma unroll
    for (int i = 0; i < 2; i++) {
      int off = i * 2048 + tid * 8;
      gload_lds16(A + (size_t)(tm + (off >> 6)) * K + k0 + (off & 63),
                  &sA[buf * 4096 + i * 2048 + w * 512]);
    }
#pragma unroll
    for (int i = 0; i < 4; i++) {
      int off = i * 2048 + tid * 8;
      gload_lds16(Bm + (size_t)(tn + (off >> 6)) * K + k0 + (off & 63),
                  &sB[buf * 8192 + i * 2048 + w * 512]);
    }
  };

  stage(0, 0);
  WAITV(0);
  BARRIER();
  int cur = 0;
  for (int kt = 0; kt < nk; kt++) {
    if (kt + 1 < nk) {
      stage(cur ^ 1, kt + 1);
      WAITV(6);
    } else {
      WAITV(0);
    }
    BARRIER();
    const bf16_t* sAb = &sA[cur * 4096];
    const bf16_t* sBb = &sB[cur * 8192];
#pragma unroll
    for (int kk = 0; kk < 2; kk++) {
      bf16x8 af[2], bfr[4];
#pragma unroll
      for (int m = 0; m < 2; m++)
        af[m] = *(const bf16x8*)&sAb[(wr * 32 + m * 16 + li) * 64 + kk * 32 + lg * 8];
#pragma unroll
      for (int n = 0; n < 4; n++)
        bfr[n] = *(const bf16x8*)&sBb[(wc * 64 + n * 16 + li) * 64 + kk * 32 + lg * 8];
#pragma unroll
      for (int m = 0; m < 2; m++)
#pragma unroll
        for (int n = 0; n < 4; n++)
          acc[m][n] = mfma16(af[m], bfr[n], acc[m][n]);
    }
    BARRIER();
    cur ^= 1;
  }

#pragma unroll
  for (int m = 0; m < 2; m++) {
    int rbase = tm + wr * 32 + m * 16 + lg * 4;
#pragma unroll
    for (int n = 0; n < 4; n++) {
      int c = tn + wc * 64 + n * 16 + li;
#pragma unroll
      for (int j = 0; j < 4; j++)
        P[(size_t)(rbase + j) * N + c] = (bf16_t)acc[m][n][j];
    }
  }
}

// ---------------- fused QKV GEMM: 64x128 tile, dbuf, counted vmcnt -------
__global__ __launch_bounds__(256) void gemm_qkv(const bf16_t* __restrict__ A,
                                                const bf16_t* __restrict__ Bm,
                                                const float* __restrict__ bq,
                                                const float* __restrict__ bk,
                                                const float* __restrict__ bv,
                                                bf16_t* __restrict__ qo,
                                                bf16_t* __restrict__ ko,
                                                bf16_t* __restrict__ vTo) {
  constexpr int K = Dc;
  __shared__ bf16_t sA[2 * 64 * 64];
  __shared__ bf16_t sB[2 * 128 * 64];
  const int tid = threadIdx.x;
  const int w = tid >> 6, l = tid & 63, lg = l >> 4, li = l & 15;
  const int wr = w >> 1, wc = w & 1;
  const int nwg = gridDim.x, cpx = nwg >> 3;  // 1152 -> 144
  const int id = blockIdx.x;
  const int tid2 = (id & 7) * cpx + (id >> 3);
  constexpr int nbx = Mrows / 64;  // 64
  const int tm = (tid2 % nbx) * 64, tn = (tid2 / nbx) * 128;
  constexpr int nk = K >> 6;       // 12

  f32x4 acc[2][4];
#pragma unroll
  for (int m = 0; m < 2; m++)
#pragma unroll
    for (int n = 0; n < 4; n++) acc[m][n] = (f32x4){0.f, 0.f, 0.f, 0.f};

  auto stage = [&](int buf, int kt) {
    const int k0 = kt * 64;
#pragma unroll
    for (int i = 0; i < 2; i++) {
      int off = i * 2048 + tid * 8;
      gload_lds16(A + (size_t)(tm + (off >> 6)) * K + k0 + (off & 63),
                  &sA[buf * 4096 + i * 2048 + w * 512]);
    }
#pragma unroll
    for (int i = 0; i < 4; i++) {
      int off = i * 2048 + tid * 8;
      gload_lds16(Bm + (size_t)(tn + (off >> 6)) * K + k0 + (off & 63),
                  &sB[buf * 8192 + i * 2048 + w * 512]);
    }
  };

  stage(0, 0);
  WAITV(0);
  BARRIER();
  int cur = 0;
  for (int kt = 0; kt < nk; kt++) {
    if (kt + 1 < nk) {
      stage(cur ^ 1, kt + 1);
      WAITV(6);
    } else {
      WAITV(0);
    }
    BARRIER();
    const bf16_t* sAb = &sA[cur * 4096];
    const bf16_t* sBb = &sB[cur * 8192];
#pragma unroll
    for (int kk = 0; kk < 2; kk++) {
      bf16x8 af[2], bfr[4];
#pragma unroll
      for (int m = 0; m < 2; m++)
        af[m] = *(const bf16x8*)&sAb[(wr * 32 + m * 16 + li) * 64 + kk * 32 + lg * 8];
#pragma unroll
      for (int n = 0; n < 4; n++)
        bfr[n] = *(const bf16x8*)&sBb[(wc * 64 + n * 16 + li) * 64 + kk * 32 + lg * 8];
#pragma unroll
      for (int m = 0; m < 2; m++)
#pragma unroll
        for (int n = 0; n < 4; n++)
          acc[m][n] = mfma16(af[m], bfr[n], acc[m][n]);
    }
    BARRIER();
    cur ^= 1;
  }

  const int which = tn / 768;  // 768 % 128 == 0 -> uniform per block
#pragma unroll
  for (int m = 0; m < 2; m++) {
    int rbase = tm + wr * 32 + m * 16 + lg * 4;
#pragma unroll
    for (int n = 0; n < 4; n++) {
      int c = tn + wc * 64 + n * 16 + li;
      int col = c - which * 768;
      if (which == 0) {
        float bvv = bq[col];
#pragma unroll
        for (int j = 0; j < 4; j++)
          qo[(size_t)(rbase + j) * Dc + col] = (bf16_t)((acc[m][n][j] + bvv) * QSCALE);
      } else if (which == 1) {
        float bvv = bk[col];
#pragma unroll
        for (int j = 0; j < 4; j++)
          ko[(size_t)(rbase + j) * Dc + col] = (bf16_t)(acc[m][n][j] + bvv);
      } else {
        float bvv = bv[col];
        int h = col >> 6, d = col & 63;
        int b = rbase >> 11, s0 = rbase & 2047;
        bf16x4 pk;
#pragma unroll
        for (int j = 0; j < 4; j++) pk[j] = (bf16_t)(acc[m][n][j] + bvv);
        *(bf16x4*)(vTo + ((size_t)(b * Hc + h) * HDc + d) * Sc + s0) = pk;
      }
    }
  }
}

// ---------------- flash attention v7 (proven version, unchanged) --------
__global__ __launch_bounds__(256) void attn7_kernel(
    const bf16_t* __restrict__ q, const bf16_t* __restrict__ k,
    const bf16_t* __restrict__ vT, const unsigned long long* __restrict__ maskT,
    bf16_t* __restrict__ ctx) {
  __shared__ __align__(16) char smem[32768];

  const int t = threadIdx.x, w = t >> 6, l = t & 63;
  const int hi = l >> 5, li = l & 31;
  const int wp = w & 1, kvh = w >> 1;
  const int gid = blockIdx.x;
  const int tid2 = (gid & 7) * 96 + (gid >> 3);
  const int bh = tid2 >> 5, qt = tid2 & 31;
  const int b = bh / Hc, h = bh - b * Hc;
  const int qrow = qt * 64 + wp * 32 + li;

  const bf16_t* qp = q + (size_t)(b * Sc + qrow) * Dc + h * HDc + hi * 8;
  bf16x8 qf[4];
#pragma unroll
  for (int dk = 0; dk < 4; dk++) qf[dk] = *(const bf16x8*)(qp + dk * 16);

  const bf16_t* kg = k + ((size_t)(b * Sc) + kvh * 1024) * Dc + h * HDc;
  const bf16_t* vg = vT + (size_t)bh * HDc * Sc + kvh * 1024;
  const unsigned long long* mg =
      maskT + (size_t)b * 32 * Sc + (size_t)(kvh * 16) * Sc + qrow;

  f32x16 o0, o1;
#pragma unroll
  for (int r = 0; r < 16; r++) { o0[r] = 0.f; o1[r] = 0.f; }
  float ps = 0.f;

  auto stage = [&](int buf, int c) {
    const int kv0 = c * 32;
    bf16_t* sk = (bf16_t*)(smem + kvh * 16384 + buf * 8192);
    bf16_t* sv = (bf16_t*)(smem + kvh * 16384 + buf * 8192 + 4096);
#pragma unroll
    for (int i = 0; i < 2; i++) {
      int s = i * 128 + wp * 64 + l;
      int row = s >> 3, ch = s & 7;
      gload_lds16(kg + (size_t)(kv0 + row) * Dc + ((ch ^ (row & 7)) * 8),
                  sk + (i * 128 + wp * 64) * 8);
    }
#pragma unroll
    for (int i = 0; i < 2; i++) {
      int s = i * 128 + wp * 64 + l;
      int row = s >> 2, ch = s & 3;
      gload_lds16(vg + (size_t)row * Sc + kv0 + ((ch ^ ((row >> 1) & 3)) * 8),
                  sv + (i * 128 + wp * 64) * 8);
    }
  };

  stage(0, 0);
  __syncthreads();
  int cur = 0;
  unsigned long long mw = 0;
#pragma unroll 2
  for (int c = 0; c < 32; c++) {
    if (c + 1 < 32) stage(cur ^ 1, c + 1);
    if ((c & 1) == 0) mw = mg[(size_t)(c >> 1) * Sc];
    unsigned msel = (c & 1) ? (unsigned)(mw >> 32) : (unsigned)mw;
    unsigned ms0 = msel >> (hi * 4);

    f32x16 sc0;
#pragma unroll
    for (int r = 0; r < 16; r++) sc0[r] = 0.f;
    const bf16_t* kb = (const bf16_t*)(smem + kvh * 16384 + cur * 8192);
    __builtin_amdgcn_s_setprio(1);
#pragma unroll
    for (int dk = 0; dk < 4; dk++) {
      int ch = dk * 2 + hi;
      bf16x8 ka0 = *(const bf16x8*)(kb + li * 64 + ((ch ^ (li & 7)) * 8));
      sc0 = mfma32(ka0, qf[dk], sc0);
    }
    __builtin_amdgcn_s_setprio(0);

    unsigned pw[8];
#pragma unroll
    for (int r = 0; r < 16; r += 2) {
      int kbit = (r & 3) + 8 * (r >> 2);
      float a0 = fexp2(sc0[r]), a1 = fexp2(sc0[r + 1]);
      a0 = ((ms0 >> kbit) & 1u) ? 0.f : a0;
      a1 = ((ms0 >> (kbit + 1)) & 1u) ? 0.f : a1;
      ps += a0 + a1;
      pw[r >> 1] = cvtpk(a0, a1);
    }
    swapl(pw[0], pw[2]);  swapl(pw[1], pw[3]);
    swapl(pw[4], pw[6]);  swapl(pw[5], pw[7]);
    bf16x8 pb0 = frag4(pw[0], pw[1], pw[2], pw[3]);
    bf16x8 pb1 = frag4(pw[4], pw[5], pw[6], pw[7]);

    const bf16_t* vb = (const bf16_t*)(smem + kvh * 16384 + cur * 8192 + 4096);
    __builtin_amdgcn_s_setprio(1);
#pragma unroll
    for (int g = 0; g < 2; g++) {
      int ch = g * 2 + hi;
      bf16x8 va0 = *(const bf16x8*)(vb + li * 32 + ((ch ^ ((li >> 1) & 3)) * 8));
      bf16x8 va1 = *(const bf16x8*)(vb + (32 + li) * 32 + ((ch ^ ((li >> 1) & 3)) * 8));
      bf16x8 pbg = (g == 0) ? pb0 : pb1;
      o0 = mfma32(va0, pbg, o0);
      o1 = mfma32(va1, pbg, o1);
    }
    __builtin_amdgcn_s_setprio(0);
    __syncthreads();
    cur ^= 1;
  }

  float* mp = (float*)(smem + 16384);
  if (kvh == 1) {
    char* base = smem + wp * 8192 + l * 128;
#pragma unroll
    for (int r = 0; r < 4; r++) {
      *(f32x4*)(base + ((r ^ (l & 7)) * 16)) =
          (f32x4){o0[r * 4], o0[r * 4 + 1], o0[r * 4 + 2], o0[r * 4 + 3]};
      *(f32x4*)(base + (((r + 4) ^ (l & 7)) * 16)) =
          (f32x4){o1[r * 4], o1[r * 4 + 1], o1[r * 4 + 2], o1[r * 4 + 3]};
    }
    mp[wp * 64 + l] = ps;
  }
  __syncthreads();
  float inv = 0.f;
  if (kvh == 0) {
    char* base = smem + wp * 8192 + l * 128;
#pragma unroll
    for (int r = 0; r < 4; r++) {
      f32x4 u = *(const f32x4*)(base + ((r ^ (l & 7)) * 16));
      f32x4 v = *(const f32x4*)(base + (((r + 4) ^ (l & 7)) * 16));
#pragma unroll
      for (int j = 0; j < 4; j++) { o0[r * 4 + j] += u[j]; o1[r * 4 + j] += v[j]; }
    }
    ps += mp[wp * 64 + l];
    float tot = ps + __shfl_xor(ps, 32, 64);
    inv = 1.f / tot;
  }
  __syncthreads();
  if (kvh == 0) {
    char* so = smem + wp * 4096;
    const int lx = li & 7;
#pragma unroll
    for (int g = 0; g < 4; g++) {
      unsigned u0 = cvtpk(o0[g * 4 + 0] * inv, o0[g * 4 + 1] * inv);
      unsigned u1 = cvtpk(o0[g * 4 + 2] * inv, o0[g * 4 + 3] * inv);
      unsigned v0 = cvtpk(o1[g * 4 + 0] * inv, o1[g * 4 + 1] * inv);
      unsigned v1 = cvtpk(o1[g * 4 + 2] * inv, o1[g * 4 + 3] * inv);
      *(uint2*)(so + li * 128 + ((g ^ lx) * 16) + hi * 8) = make_uint2(u0, u1);
      *(uint2*)(so + li * 128 + (((g + 4) ^ lx) * 16) + hi * 8) = make_uint2(v0, v1);
    }
    __builtin_amdgcn_s_waitcnt(0);
    bf16_t* cbase = ctx + (size_t)(b * Sc + qt * 64 + wp * 32) * Dc + h * HDc;
#pragma unroll
    for (int i = 0; i < 4; i++) {
      int s = i * 64 + l;
      int row = s >> 3, ch = s & 7;
      bf16x8 vv = *(const bf16x8*)(so + row * 128 + ((ch ^ (row & 7)) * 16));
      *(bf16x8*)(cbase + (size_t)row * Dc + ch * 8) = vv;
    }
  }
}

// ---- fused split-K reduce + bias + residual + LayerNorm (bf16 streams) --
// v = p0 + p1 + bias[d] + res;  x = LN(v)*g + b -> xb (bf16), optionally xo.
// res aliases xb (read-before-write per element, per-row blocks: safe).
__global__ __launch_bounds__(256) void ln_fuse_kernel(const bf16_t* __restrict__ p0,
                                                      const bf16_t* __restrict__ p1,
                                                      const float* __restrict__ bias,
                                                      const bf16_t* res,
                                                      const float* __restrict__ g,
                                                      const float* __restrict__ bb,
                                                      float* xo, bf16_t* xb) {
  const int row = blockIdx.x;
  const int t = threadIdx.x;
  const size_t base = (size_t)row * Dc;
  float v0 = (float)p0[base + t] + (float)p1[base + t] + bias[t] + (float)res[base + t];
  float v1 = (float)p0[base + t + 256] + (float)p1[base + t + 256] + bias[t + 256] +
             (float)res[base + t + 256];
  float v2 = (float)p0[base + t + 512] + (float)p1[base + t + 512] + bias[t + 512] +
             (float)res[base + t + 512];
  float s = v0 + v1 + v2;
  float sq = v0 * v0 + v1 * v1 + v2 * v2;
#pragma unroll
  for (int ofs = 1; ofs < 64; ofs <<= 1) {
    s += __shfl_xor(s, ofs, 64);
    sq += __shfl_xor(sq, ofs, 64);
  }
  __shared__ float red[8];
  const int w = t >> 6, l = t & 63;
  if (l == 0) { red[w] = s; red[4 + w] = sq; }
  __syncthreads();
  s = red[0] + red[1] + red[2] + red[3];
  sq = red[4] + red[5] + red[6] + red[7];
  const float mean = s * (1.f / Dc);
  const float var = sq * (1.f / Dc) - mean * mean;
  const float rs = rsqrtf(var + 1e-5f);
  bf16_t* pb = xb + base;
#pragma unroll
  for (int i = 0; i < 3; i++) {
    int d = t + i * 256;
    float vv = (i == 0 ? v0 : (i == 1 ? v1 : v2));
    float ov = (vv - mean) * rs * g[d] + bb[d];
    if (xo) xo[base + d] = ov;
    pb[d] = (bf16_t)ov;
  }
}

// ---------------- launcher ----------------

extern "C" void kernel_launch(void* const* d_in, const int* in_sizes, int n_in,
                              void* d_out, int out_size, void* d_ws, size_t ws_size,
                              hipStream_t stream) {
  const float* inputs = (const float*)d_in[0];
  const int* amask = (const int*)d_in[1];
  const float* Wq = (const float*)d_in[2];
  const float* bq = (const float*)d_in[3];
  const float* Wk = (const float*)d_in[4];
  const float* bk = (const float*)d_in[5];
  const float* Wv = (const float*)d_in[6];
  const float* bv = (const float*)d_in[7];
  const float* Wo = (const float*)d_in[8];
  const float* bo = (const float*)d_in[9];
  const float* ln1_g = (const float*)d_in[10];
  const float* ln1_b = (const float*)d_in[11];
  const float* W1 = (const float*)d_in[12];
  const float* b1 = (const float*)d_in[13];
  const float* W2 = (const float*)d_in[14];
  const float* b2 = (const float*)d_in[15];
  const float* ln2_g = (const float*)d_in[16];
  const float* ln2_b = (const float*)d_in[17];
  float* xout = (float*)d_out;

  char* p = (char*)d_ws;
  auto carve = [&](size_t bytes) -> char* {
    char* r = p;
    p += (bytes + 255) & ~(size_t)255;
    return r;
  };
  const size_t nDD = (size_t)Lc * Dc * Dc;
  const size_t nFD = (size_t)Lc * Fc * Dc;
  const size_t nAct = nActC;
  const size_t nHid = (size_t)Mrows * Fc;

  bf16_t* wqkv16 = (bf16_t*)carve(nDD * 3 * 2);
  bf16_t* wo16 = (bf16_t*)carve(nDD * 2);
  bf16_t* w1_16 = (bf16_t*)carve(nFD * 2);
  bf16_t* w2_16 = (bf16_t*)carve(nFD * 2);
  bf16_t* xb = (bf16_t*)carve(nAct * 2);
  bf16_t* q16 = (bf16_t*)carve(nAct * 2);
  bf16_t* k16 = (bf16_t*)carve(nAct * 2);
  bf16_t* vTb = (bf16_t*)carve(nAct * 2);
  bf16_t* ctx = (bf16_t*)carve(nAct * 2);
  bf16_t* h16 = (bf16_t*)carve(nHid * 2);
  bf16_t* pk0 = (bf16_t*)carve(nAct * 2);   // split-K partial 0 (bf16)
  bf16_t* pk1 = (bf16_t*)carve(nAct * 2);   // split-K partial 1 (bf16)
  unsigned long long* maskb = (unsigned long long*)carve((size_t)Bc * (Sc / 64) * Sc * 8);
  (void)ws_size; (void)n_in; (void)in_sizes; (void)out_size;

  dim3 blk(256);

  mask_packT_kernel<<<(int)((size_t)Bc * Sc * Sc / 256), blk, 0, stream>>>(amask, maskb);
  cvt_weights_kernel<<<(int)((4 * nDD + 2 * nFD) / 1024), blk, 0, stream>>>(
      Wq, Wk, Wv, Wo, W1, W2, wqkv16, wo16, w1_16, w2_16);
  init_x_kernel<<<(int)(nAct / 1024), blk, 0, stream>>>(inputs, xb, (int)nAct);

  for (int i = 0; i < Lc; i++) {
    const bf16_t* wqkv_l = wqkv16 + (size_t)i * 3 * Dc * Dc;
    const bf16_t* wo_l = wo16 + (size_t)i * Dc * Dc;
    const bf16_t* w1_l = w1_16 + (size_t)i * Fc * Dc;
    const bf16_t* w2_l = w2_16 + (size_t)i * Dc * Fc;

    gemm_qkv<<<1152, blk, 0, stream>>>(
        xb, wqkv_l, bq + (size_t)i * Dc, bk + (size_t)i * Dc, bv + (size_t)i * Dc,
        q16, k16, vTb);

    attn7_kernel<<<768, blk, 0, stream>>>(q16, k16, vTb, maskb, ctx);

    // Wo projection, split-K=2 -> bf16 partials; LN1 fuses reduce+bias+res.
    gemm_sk<<<768, blk, 0, stream>>>(ctx, wo_l, pk0, pk1, Mrows, Dc, Dc);
    ln_fuse_kernel<<<Mrows, blk, 0, stream>>>(pk0, pk1, bo + (size_t)i * Dc, xb,
                                              ln1_g + (size_t)i * Dc,
                                              ln1_b + (size_t)i * Dc, nullptr, xb);
    gemm_ffn1<<<1536, blk, 0, stream>>>(
        xb, w1_l, b1 + (size_t)i * Fc, h16, Mrows, Fc, Dc);
    // FFN2, split-K=2 -> bf16 partials; LN2 fuses reduce+bias+res.
    gemm_sk<<<768, blk, 0, stream>>>(h16, w2_l, pk0, pk1, Mrows, Dc, Fc);
    ln_fuse_kernel<<<Mrows, blk, 0, stream>>>(pk0, pk1, b2 + (size_t)i * Dc, xb,
                                              ln2_g + (size_t)i * Dc,
                                              ln2_b + (size_t)i * Dc,
                                              (i == Lc - 1) ? xout : nullptr, xb);
  }
}